// Round 5
// baseline (880.809 us; speedup 1.0000x reference)
//
#include <hip/hip_runtime.h>
#include <hip/hip_bf16.h>

typedef __bf16 bf16_t;
typedef __bf16 bf16x8 __attribute__((ext_vector_type(8)));
typedef float f32x4 __attribute__((ext_vector_type(4)));

#define MTOT 8192   // B*M tokens
#define CDIM 1024
#define HEADS 8
#define DQK 16
#define DV 128
#define QKD 128
#define SEQ 2048
#define NPHASE 4
#define HPP (HEADS / NPHASE)   // heads per phase = 2

// load 8 consecutive fp32, pack to bf16x8 (in-register convert)
__device__ inline bf16x8 ld_cvt8(const float* p) {
    float4 a = *reinterpret_cast<const float4*>(p);
    float4 b = *reinterpret_cast<const float4*>(p + 4);
    bf16x8 v = { (bf16_t)a.x, (bf16_t)a.y, (bf16_t)a.z, (bf16_t)a.w,
                 (bf16_t)b.x, (bf16_t)b.y, (bf16_t)b.z, (bf16_t)b.w };
    return v;
}

// ---------------------------------------------------------------------------
// Y[m][n] = sum_k X[m][k] * W[n][k] + bias[n]; X, W fp32, MFMA in bf16.
// mode 0: store row-major out[m][n] bf16 (Q, K: N=128, nbase=0)
// mode 1: V phase-transposed bf16: out[((b*HPP + hl)*128 + dv)*SEQ + ml]
// ---------------------------------------------------------------------------
__global__ __launch_bounds__(256) void qkv_gemm(
    const float* __restrict__ X, const float* __restrict__ W,
    const float* __restrict__ bias, bf16_t* __restrict__ out,
    int N, int nbase, int mode)
{
    const int lane = threadIdx.x & 63;
    const int wave = threadIdx.x >> 6;
    const int c = lane & 15;
    const int q = lane >> 4;
    const int m0 = blockIdx.y * 64 + wave * 16;
    const int n0 = blockIdx.x * 64;          // local n within this launch

    f32x4 acc[4] = {};

    const float* xrow  = X + (size_t)(m0 + c) * CDIM + q * 8;
    const float* wbase = W + (size_t)(nbase + n0 + c) * CDIM + q * 8;

    for (int k0 = 0; k0 < CDIM; k0 += 32) {
        bf16x8 a = ld_cvt8(xrow + k0);
        #pragma unroll
        for (int nt = 0; nt < 4; ++nt) {
            bf16x8 bfr = ld_cvt8(wbase + (size_t)nt * 16 * CDIM + k0);
            acc[nt] = __builtin_amdgcn_mfma_f32_16x16x32_bf16(a, bfr, acc[nt], 0, 0, 0);
        }
    }

    #pragma unroll
    for (int nt = 0; nt < 4; ++nt) {
        const int nl = n0 + nt * 16 + c;       // local col
        const float bb = bias[nbase + nl];
        if (mode == 0) {
            #pragma unroll
            for (int r = 0; r < 4; ++r) {
                const int m = m0 + q * 4 + r;
                out[(size_t)m * N + nl] = (bf16_t)(acc[nt][r] + bb);
            }
        } else {
            const int mg = m0 + q * 4;
            const int bidx = mg >> 11;         // batch
            const int ml = mg & 2047;          // m within batch
            const int hl = nl >> 7;            // head within phase
            const int dv = nl & 127;
            struct alignas(8) V4 { bf16_t e0, e1, e2, e3; };
            V4 v{ (bf16_t)(acc[nt][0] + bb), (bf16_t)(acc[nt][1] + bb),
                  (bf16_t)(acc[nt][2] + bb), (bf16_t)(acc[nt][3] + bb) };
            *reinterpret_cast<V4*>(out + ((size_t)(bidx * HPP + hl) * DV + dv) * SEQ + ml) = v;
        }
    }
}

// ---------------------------------------------------------------------------
// Flash attention, one phase = HPP heads. One WG = one (b, h_local) x 64 rows.
// Output is FP32 (reference output dtype).
// ---------------------------------------------------------------------------
__global__ __launch_bounds__(256) void attn_kernel(
    const bf16_t* __restrict__ Q, const bf16_t* __restrict__ K,
    const bf16_t* __restrict__ VtP, const float* __restrict__ X,
    const float* __restrict__ gptr, float* __restrict__ out, int h0)
{
    __shared__ alignas(16) bf16_t Vs[128][72];     // [dv][key] pad 64->72
    __shared__ alignas(16) bf16_t Ps[4][16][72];   // per-wave P tile [m][n]

    const int lane = threadIdx.x & 63;
    const int wave = threadIdx.x >> 6;
    const int c = lane & 15;
    const int q = lane >> 4;
    const int bh = blockIdx.y;                 // [0, 4*HPP)
    const int b = bh >> 1, hl = bh & (HPP - 1);
    const int h = h0 + hl;
    const int m0 = blockIdx.x * 64;

    // Q A-fragment (k=0..15 in quads 0,1; quads 2,3 zero => pads K to 32)
    bf16x8 aq = {};
    if (q < 2)
        aq = *reinterpret_cast<const bf16x8*>(
            Q + (size_t)(b * SEQ + m0 + wave * 16 + c) * QKD + h * DQK + q * 8);

    float mi[4], li[4];
    #pragma unroll
    for (int r = 0; r < 4; ++r) { mi[r] = -1e30f; li[r] = 0.f; }
    f32x4 o[8] = {};

    const bf16_t* Vhead = VtP + (size_t)(b * HPP + hl) * DV * SEQ;

    for (int n0 = 0; n0 < SEQ; n0 += 64) {
        __syncthreads();
        {
            const int dv = threadIdx.x >> 1;
            const int seg = threadIdx.x & 1;
            const bf16_t* src = Vhead + (size_t)dv * SEQ + n0 + seg * 32;
            #pragma unroll
            for (int i = 0; i < 4; ++i)
                *reinterpret_cast<bf16x8*>(&Vs[dv][seg * 32 + i * 8]) =
                    *reinterpret_cast<const bf16x8*>(src + i * 8);
        }
        __syncthreads();

        // S = Q K^T for this wave's 16 rows x 64 keys
        f32x4 s[4];
        #pragma unroll
        for (int st = 0; st < 4; ++st) {
            bf16x8 bk = {};
            if (q < 2)
                bk = *reinterpret_cast<const bf16x8*>(
                    K + (size_t)(b * SEQ + n0 + st * 16 + c) * QKD + h * DQK + q * 8);
            f32x4 z = {};
            s[st] = __builtin_amdgcn_mfma_f32_16x16x32_bf16(aq, bk, z, 0, 0, 0);
        }

        // scale 1/sqrt(16) then LeakyReLU(0.2)
        #pragma unroll
        for (int st = 0; st < 4; ++st)
            #pragma unroll
            for (int r = 0; r < 4; ++r) {
                float v = s[st][r] * 0.25f;
                s[st][r] = v >= 0.f ? v : 0.2f * v;
            }

        // online softmax: row stats across subtiles + 16 lanes of each quad
        float mx[4];
        #pragma unroll
        for (int r = 0; r < 4; ++r)
            mx[r] = fmaxf(fmaxf(s[0][r], s[1][r]), fmaxf(s[2][r], s[3][r]));
        #pragma unroll
        for (int off = 1; off < 16; off <<= 1)
            #pragma unroll
            for (int r = 0; r < 4; ++r)
                mx[r] = fmaxf(mx[r], __shfl_xor(mx[r], off));

        float alpha[4], rs[4];
        #pragma unroll
        for (int r = 0; r < 4; ++r) {
            const float mnew = fmaxf(mi[r], mx[r]);
            alpha[r] = __expf(mi[r] - mnew);
            mi[r] = mnew;
            rs[r] = 0.f;
        }
        #pragma unroll
        for (int st = 0; st < 4; ++st)
            #pragma unroll
            for (int r = 0; r < 4; ++r) {
                const float p = __expf(s[st][r] - mi[r]);
                s[st][r] = p;
                rs[r] += p;
            }
        #pragma unroll
        for (int off = 1; off < 16; off <<= 1)
            #pragma unroll
            for (int r = 0; r < 4; ++r)
                rs[r] += __shfl_xor(rs[r], off);
        #pragma unroll
        for (int r = 0; r < 4; ++r)
            li[r] = li[r] * alpha[r] + rs[r];

        #pragma unroll
        for (int dvt = 0; dvt < 8; ++dvt)
            #pragma unroll
            for (int r = 0; r < 4; ++r)
                o[dvt][r] *= alpha[r];

        // P: C-layout -> LDS (A-layout source)
        #pragma unroll
        for (int st = 0; st < 4; ++st)
            #pragma unroll
            for (int r = 0; r < 4; ++r)
                Ps[wave][q * 4 + r][st * 16 + c] = (bf16_t)s[st][r];

        __syncthreads();

        // O += P V
        #pragma unroll
        for (int kt = 0; kt < 2; ++kt) {
            bf16x8 pa = *reinterpret_cast<const bf16x8*>(&Ps[wave][c][kt * 32 + q * 8]);
            #pragma unroll
            for (int dvt = 0; dvt < 8; ++dvt) {
                bf16x8 bv = *reinterpret_cast<const bf16x8*>(&Vs[dvt * 16 + c][kt * 32 + q * 8]);
                o[dvt] = __builtin_amdgcn_mfma_f32_16x16x32_bf16(pa, bv, o[dvt], 0, 0, 0);
            }
        }
    }

    // epilogue: out = gamma * (O / l) + x, FP32 stores
    const float g = gptr[0];
    float inv[4];
    #pragma unroll
    for (int r = 0; r < 4; ++r) inv[r] = 1.f / li[r];
    #pragma unroll
    for (int dvt = 0; dvt < 8; ++dvt)
        #pragma unroll
        for (int r = 0; r < 4; ++r) {
            const int ml = m0 + wave * 16 + q * 4 + r;
            const size_t idx = (size_t)(b * SEQ + ml) * CDIM + h * DV + dvt * 16 + c;
            out[idx] = g * (o[dvt][r] * inv[r]) + X[idx];
        }
}

extern "C" void kernel_launch(void* const* d_in, const int* in_sizes, int n_in,
                              void* d_out, int out_size, void* d_ws, size_t ws_size,
                              hipStream_t stream) {
    // Reference dtypes: ALL fp32 in, fp32 OUT.
    const float* X  = (const float*)d_in[0];
    const float* Wq = (const float*)d_in[1];
    const float* bq = (const float*)d_in[2];
    const float* Wk = (const float*)d_in[3];
    const float* bk = (const float*)d_in[4];
    const float* Wv = (const float*)d_in[5];
    const float* bv = (const float*)d_in[6];
    const float* g  = (const float*)d_in[7];
    float* out = (float*)d_out;

    // workspace (bf16 elems): Q 2MB, K 2MB, VtP 4MB => 8MB total
    bf16_t* Qw  = (bf16_t*)d_ws;
    bf16_t* Kw  = Qw + (size_t)MTOT * QKD;
    bf16_t* VtP = Kw + (size_t)MTOT * QKD;

    dim3 blk(256);
    hipLaunchKernelGGL(qkv_gemm, dim3(2, 128), blk, 0, stream, X, Wq, bq, Qw, QKD, 0, 0);
    hipLaunchKernelGGL(qkv_gemm, dim3(2, 128), blk, 0, stream, X, Wk, bk, Kw, QKD, 0, 0);

    for (int ph = 0; ph < NPHASE; ++ph) {
        const int nbase = ph * (HPP * DV);     // 256 V-channels per phase
        hipLaunchKernelGGL(qkv_gemm, dim3(HPP * DV / 64, 128), blk, 0, stream,
                           X, Wv, bv, VtP, HPP * DV, nbase, 1);
        hipLaunchKernelGGL(attn_kernel, dim3(SEQ / 64, 4 * HPP), blk, 0, stream,
                           Qw, Kw, VtP, X, g, out, ph * HPP);
    }
}

// Round 6
// 580.871 us; speedup vs baseline: 1.5164x; 1.5164x over previous
//
#include <hip/hip_runtime.h>
#include <hip/hip_bf16.h>

typedef __bf16 bf16_t;
typedef __bf16 bf16x8 __attribute__((ext_vector_type(8)));
typedef float f32x4 __attribute__((ext_vector_type(4)));

#define MTOT 8192   // B*M tokens
#define CDIM 1024
#define HEADS 8
#define DQK 16
#define DV 128
#define QKD 128
#define SEQ 2048

// load 8 consecutive fp32, pack to bf16x8 (in-register convert)
__device__ inline bf16x8 ld_cvt8(const float* p) {
    float4 a = *reinterpret_cast<const float4*>(p);
    float4 b = *reinterpret_cast<const float4*>(p + 4);
    bf16x8 v = { (bf16_t)a.x, (bf16_t)a.y, (bf16_t)a.z, (bf16_t)a.w,
                 (bf16_t)b.x, (bf16_t)b.y, (bf16_t)b.z, (bf16_t)b.w };
    return v;
}

// ---------------------------------------------------------------------------
// Shared GEMM core: one WG computes a 64x64 tile of Y = X W^T + b.
// Stores per segment: Q/K row-major [m][128]; V transposed per head
// Vt[((b*hcnt + h)*128 + dv)*SEQ + ml].
// ---------------------------------------------------------------------------
__device__ inline void gemm_tile(
    const float* __restrict__ X, const float* __restrict__ W,
    const float* __restrict__ bias, int wn0, int m0q, int lane, int wave,
    f32x4 acc[4])
{
    const int c = lane & 15;
    const int q = lane >> 4;
    const float* xrow  = X + (size_t)(m0q + c) * CDIM + q * 8;
    const float* wbase = W + (size_t)(wn0 + c) * CDIM + q * 8;
    for (int k0 = 0; k0 < CDIM; k0 += 32) {
        bf16x8 a = ld_cvt8(xrow + k0);
        #pragma unroll
        for (int nt = 0; nt < 4; ++nt) {
            bf16x8 bfr = ld_cvt8(wbase + (size_t)nt * 16 * CDIM + k0);
            acc[nt] = __builtin_amdgcn_mfma_f32_16x16x32_bf16(a, bfr, acc[nt], 0, 0, 0);
        }
    }
}

// Fused Q+K+V projection: grid (20, 128). bx 0-1: Q, 2-3: K, 4-19: V.
__global__ __launch_bounds__(256) void qkv_fused(
    const float* __restrict__ X,
    const float* __restrict__ Wq, const float* __restrict__ bq,
    const float* __restrict__ Wk, const float* __restrict__ bk,
    const float* __restrict__ Wv, const float* __restrict__ bv,
    bf16_t* __restrict__ Qw, bf16_t* __restrict__ Kw, bf16_t* __restrict__ Vt)
{
    const int lane = threadIdx.x & 63;
    const int wave = threadIdx.x >> 6;
    const int c = lane & 15;
    const int q = lane >> 4;
    const int bx = blockIdx.x;
    const int m0 = blockIdx.y * 64 + wave * 16;

    const float* W; const float* bias; int n0;
    if (bx < 2)      { W = Wq; bias = bq; n0 = bx * 64; }
    else if (bx < 4) { W = Wk; bias = bk; n0 = (bx - 2) * 64; }
    else             { W = Wv; bias = bv; n0 = (bx - 4) * 64; }

    f32x4 acc[4] = {};
    gemm_tile(X, W, bias, n0, m0, lane, wave, acc);

    #pragma unroll
    for (int nt = 0; nt < 4; ++nt) {
        const int nl = n0 + nt * 16 + c;
        const float bb = bias[nl];
        if (bx < 4) {
            bf16_t* dst = (bx < 2) ? Qw : Kw;
            #pragma unroll
            for (int r = 0; r < 4; ++r) {
                const int m = m0 + q * 4 + r;
                dst[(size_t)m * QKD + nl] = (bf16_t)(acc[nt][r] + bb);
            }
        } else {
            const int mg = m0 + q * 4;
            const int bidx = mg >> 11;         // batch
            const int ml = mg & 2047;          // m within batch
            const int h = nl >> 7;             // head
            const int dv = nl & 127;
            struct alignas(8) V4 { bf16_t e0, e1, e2, e3; };
            V4 v{ (bf16_t)(acc[nt][0] + bb), (bf16_t)(acc[nt][1] + bb),
                  (bf16_t)(acc[nt][2] + bb), (bf16_t)(acc[nt][3] + bb) };
            *reinterpret_cast<V4*>(Vt + ((size_t)(bidx * HEADS + h) * DV + dv) * SEQ + ml) = v;
        }
    }
}

// Phased fallback gemm (V only, phase-local head count hpl)
__global__ __launch_bounds__(256) void qkv_gemm(
    const float* __restrict__ X, const float* __restrict__ W,
    const float* __restrict__ bias, bf16_t* __restrict__ out,
    int N, int nbase, int mode, int hpl)
{
    const int lane = threadIdx.x & 63;
    const int wave = threadIdx.x >> 6;
    const int c = lane & 15;
    const int q = lane >> 4;
    const int m0 = blockIdx.y * 64 + wave * 16;
    const int n0 = blockIdx.x * 64;

    f32x4 acc[4] = {};
    gemm_tile(X, W, bias, nbase + n0, m0, lane, wave, acc);

    #pragma unroll
    for (int nt = 0; nt < 4; ++nt) {
        const int nl = n0 + nt * 16 + c;
        const float bb = bias[nbase + nl];
        if (mode == 0) {
            #pragma unroll
            for (int r = 0; r < 4; ++r) {
                const int m = m0 + q * 4 + r;
                out[(size_t)m * N + nl] = (bf16_t)(acc[nt][r] + bb);
            }
        } else {
            const int mg = m0 + q * 4;
            const int bidx = mg >> 11;
            const int ml = mg & 2047;
            const int hl = nl >> 7;
            const int dv = nl & 127;
            struct alignas(8) V4 { bf16_t e0, e1, e2, e3; };
            V4 v{ (bf16_t)(acc[nt][0] + bb), (bf16_t)(acc[nt][1] + bb),
                  (bf16_t)(acc[nt][2] + bb), (bf16_t)(acc[nt][3] + bb) };
            *reinterpret_cast<V4*>(out + ((size_t)(bidx * hpl + hl) * DV + dv) * SEQ + ml) = v;
        }
    }
}

// ---------------------------------------------------------------------------
// Flash attention. blockIdx.y = b*hpl + hl, hpl = 1<<hshift heads in this
// launch's Vt buffer; global head = h0 + hl. One WG = 64 query rows.
// ---------------------------------------------------------------------------
__global__ __launch_bounds__(256) void attn_kernel(
    const bf16_t* __restrict__ Q, const bf16_t* __restrict__ K,
    const bf16_t* __restrict__ VtP, const float* __restrict__ X,
    const float* __restrict__ gptr, float* __restrict__ out,
    int h0, int hshift)
{
    __shared__ alignas(16) bf16_t Vs[128][72];     // [dv][key] pad 64->72
    __shared__ alignas(16) bf16_t Ps[4][16][72];   // per-wave P tile [m][n]

    const int lane = threadIdx.x & 63;
    const int wave = threadIdx.x >> 6;
    const int c = lane & 15;
    const int q = lane >> 4;
    const int bh = blockIdx.y;
    const int b = bh >> hshift, hl = bh & ((1 << hshift) - 1);
    const int h = h0 + hl;
    const int m0 = blockIdx.x * 64;

    bf16x8 aq = {};
    if (q < 2)
        aq = *reinterpret_cast<const bf16x8*>(
            Q + (size_t)(b * SEQ + m0 + wave * 16 + c) * QKD + h * DQK + q * 8);

    float mi[4], li[4];
    #pragma unroll
    for (int r = 0; r < 4; ++r) { mi[r] = -1e30f; li[r] = 0.f; }
    f32x4 o[8] = {};

    const bf16_t* Vhead = VtP + (size_t)((b << hshift) + hl) * DV * SEQ;

    for (int n0 = 0; n0 < SEQ; n0 += 64) {
        __syncthreads();
        {
            const int dv = threadIdx.x >> 1;
            const int seg = threadIdx.x & 1;
            const bf16_t* src = Vhead + (size_t)dv * SEQ + n0 + seg * 32;
            #pragma unroll
            for (int i = 0; i < 4; ++i)
                *reinterpret_cast<bf16x8*>(&Vs[dv][seg * 32 + i * 8]) =
                    *reinterpret_cast<const bf16x8*>(src + i * 8);
        }
        __syncthreads();

        f32x4 s[4];
        #pragma unroll
        for (int st = 0; st < 4; ++st) {
            bf16x8 bk = {};
            if (q < 2)
                bk = *reinterpret_cast<const bf16x8*>(
                    K + (size_t)(b * SEQ + n0 + st * 16 + c) * QKD + h * DQK + q * 8);
            f32x4 z = {};
            s[st] = __builtin_amdgcn_mfma_f32_16x16x32_bf16(aq, bk, z, 0, 0, 0);
        }

        #pragma unroll
        for (int st = 0; st < 4; ++st)
            #pragma unroll
            for (int r = 0; r < 4; ++r) {
                float v = s[st][r] * 0.25f;
                s[st][r] = v >= 0.f ? v : 0.2f * v;
            }

        float mx[4];
        #pragma unroll
        for (int r = 0; r < 4; ++r)
            mx[r] = fmaxf(fmaxf(s[0][r], s[1][r]), fmaxf(s[2][r], s[3][r]));
        #pragma unroll
        for (int off = 1; off < 16; off <<= 1)
            #pragma unroll
            for (int r = 0; r < 4; ++r)
                mx[r] = fmaxf(mx[r], __shfl_xor(mx[r], off));

        float alpha[4], rs[4];
        #pragma unroll
        for (int r = 0; r < 4; ++r) {
            const float mnew = fmaxf(mi[r], mx[r]);
            alpha[r] = __expf(mi[r] - mnew);
            mi[r] = mnew;
            rs[r] = 0.f;
        }
        #pragma unroll
        for (int st = 0; st < 4; ++st)
            #pragma unroll
            for (int r = 0; r < 4; ++r) {
                const float p = __expf(s[st][r] - mi[r]);
                s[st][r] = p;
                rs[r] += p;
            }
        #pragma unroll
        for (int off = 1; off < 16; off <<= 1)
            #pragma unroll
            for (int r = 0; r < 4; ++r)
                rs[r] += __shfl_xor(rs[r], off);
        #pragma unroll
        for (int r = 0; r < 4; ++r)
            li[r] = li[r] * alpha[r] + rs[r];

        #pragma unroll
        for (int dvt = 0; dvt < 8; ++dvt)
            #pragma unroll
            for (int r = 0; r < 4; ++r)
                o[dvt][r] *= alpha[r];

        #pragma unroll
        for (int st = 0; st < 4; ++st)
            #pragma unroll
            for (int r = 0; r < 4; ++r)
                Ps[wave][q * 4 + r][st * 16 + c] = (bf16_t)s[st][r];

        __syncthreads();

        #pragma unroll
        for (int kt = 0; kt < 2; ++kt) {
            bf16x8 pa = *reinterpret_cast<const bf16x8*>(&Ps[wave][c][kt * 32 + q * 8]);
            #pragma unroll
            for (int dvt = 0; dvt < 8; ++dvt) {
                bf16x8 bv = *reinterpret_cast<const bf16x8*>(&Vs[dvt * 16 + c][kt * 32 + q * 8]);
                o[dvt] = __builtin_amdgcn_mfma_f32_16x16x32_bf16(pa, bv, o[dvt], 0, 0, 0);
            }
        }
    }

    const float g = gptr[0];
    float inv[4];
    #pragma unroll
    for (int r = 0; r < 4; ++r) inv[r] = 1.f / li[r];
    #pragma unroll
    for (int dvt = 0; dvt < 8; ++dvt)
        #pragma unroll
        for (int r = 0; r < 4; ++r) {
            const int ml = m0 + wave * 16 + q * 4 + r;
            const size_t idx = (size_t)(b * SEQ + ml) * CDIM + h * DV + dvt * 16 + c;
            out[idx] = g * (o[dvt][r] * inv[r]) + X[idx];
        }
}

extern "C" void kernel_launch(void* const* d_in, const int* in_sizes, int n_in,
                              void* d_out, int out_size, void* d_ws, size_t ws_size,
                              hipStream_t stream) {
    const float* X  = (const float*)d_in[0];
    const float* Wq = (const float*)d_in[1];
    const float* bq = (const float*)d_in[2];
    const float* Wk = (const float*)d_in[3];
    const float* bk = (const float*)d_in[4];
    const float* Wv = (const float*)d_in[5];
    const float* bv = (const float*)d_in[6];
    const float* g  = (const float*)d_in[7];
    float* out = (float*)d_out;

    bf16_t* Qw = (bf16_t*)d_ws;
    bf16_t* Kw = Qw + (size_t)MTOT * QKD;
    bf16_t* Vt = Kw + (size_t)MTOT * QKD;

    dim3 blk(256);
    const size_t fused_ws = (size_t)(MTOT * QKD * 2 + MTOT * CDIM) * sizeof(bf16_t); // 20 MB

    if (ws_size >= fused_ws) {
        // Full-occupancy path: one fused QKV gemm (2560 WGs), one attn (1024 WGs)
        hipLaunchKernelGGL(qkv_fused, dim3(20, 128), blk, 0, stream,
                           X, Wq, bq, Wk, bk, Wv, bv, Qw, Kw, Vt);
        hipLaunchKernelGGL(attn_kernel, dim3(SEQ / 64, 4 * HEADS), blk, 0, stream,
                           Qw, Kw, Vt, X, g, out, 0, 3);
    } else {
        // 8 MB fallback: 4 phases x 2 heads (proven in R5)
        hipLaunchKernelGGL(qkv_gemm, dim3(2, 128), blk, 0, stream, X, Wq, bq, Qw, QKD, 0, 0, 2);
        hipLaunchKernelGGL(qkv_gemm, dim3(2, 128), blk, 0, stream, X, Wk, bk, Kw, QKD, 0, 0, 2);
        for (int ph = 0; ph < 4; ++ph) {
            hipLaunchKernelGGL(qkv_gemm, dim3(4, 128), blk, 0, stream,
                               X, Wv, bv, Vt, 256, ph * 256, 1, 2);
            hipLaunchKernelGGL(attn_kernel, dim3(SEQ / 64, 8), blk, 0, stream,
                               Qw, Kw, Vt, X, g, out, ph * 2, 1);
        }
    }
}

// Round 7
// 283.504 us; speedup vs baseline: 3.1069x; 2.0489x over previous
//
#include <hip/hip_runtime.h>
#include <hip/hip_bf16.h>

typedef __bf16 bf16_t;
typedef __bf16 bf16x8 __attribute__((ext_vector_type(8)));
typedef float f32x4 __attribute__((ext_vector_type(4)));
typedef float f32x16 __attribute__((ext_vector_type(16)));

#define MTOT 8192
#define CDIM 1024
#define HEADS 8
#define DV 128
#define QKD 128
#define SEQ 2048
#define QSCALE 0.3606737602222409f   // 0.25 * log2(e): folded softmax scale, exp->exp2

struct alignas(8) B4 { bf16_t a, b, c, d; };

__device__ inline bf16x8 cvt8(float4 a, float4 b) {
    bf16x8 v = { (bf16_t)a.x, (bf16_t)a.y, (bf16_t)a.z, (bf16_t)a.w,
                 (bf16_t)b.x, (bf16_t)b.y, (bf16_t)b.z, (bf16_t)b.w };
    return v;
}

// ---------------------------------------------------------------------------
// QKV projection, LDS-staged 128x128 tile, BK=64. grid (10, 64).
// bx 0 -> Q (scaled by QSCALE), bx 1 -> K, bx 2..9 -> V head (bx-2) transposed.
// LDS col-blocks (8 bf16 = 16B) XOR-swizzled by ((row>>3)&3) to kill the
// row+-8 bank alias of the 72-elem stride.
// ---------------------------------------------------------------------------
__global__ __launch_bounds__(256, 2) void qkv_gemm2(
    const float* __restrict__ X,
    const float* __restrict__ Wq, const float* __restrict__ bq,
    const float* __restrict__ Wk, const float* __restrict__ bk,
    const float* __restrict__ Wv, const float* __restrict__ bv,
    bf16_t* __restrict__ Qw, bf16_t* __restrict__ Kw, bf16_t* __restrict__ Vt)
{
    __shared__ alignas(16) bf16_t As[128][72];
    __shared__ alignas(16) bf16_t Bs[128][72];

    const int tid  = threadIdx.x;
    const int lane = tid & 63, wave = tid >> 6;
    const int c = lane & 15, q = lane >> 4;
    const int rw = wave & 1, cw = wave >> 1;
    const int m0 = blockIdx.y * 128;
    const int nt_idx = blockIdx.x;

    const float* W; const float* bias;
    if (nt_idx == 0)      { W = Wq; bias = bq; }
    else if (nt_idx == 1) { W = Wk; bias = bk; }
    else { W = Wv + (size_t)(nt_idx - 2) * DV * CDIM; bias = bv + (nt_idx - 2) * DV; }

    const int srow = tid >> 1, sseg = tid & 1;
    const int swr = (srow >> 3) & 3;
    const float* ax = X + (size_t)(m0 + srow) * CDIM + sseg * 32;
    const float* bx = W + (size_t)srow * CDIM + sseg * 32;

    f32x4 acc[16] = {};

    for (int k0 = 0; k0 < CDIM; k0 += 64) {
        __syncthreads();
        #pragma unroll
        for (int i = 0; i < 4; ++i) {
            const int ph = (sseg * 4 + i) ^ swr;
            float4 a0 = *(const float4*)(ax + k0 + i * 8);
            float4 a1 = *(const float4*)(ax + k0 + i * 8 + 4);
            *(bf16x8*)&As[srow][ph * 8] = cvt8(a0, a1);
            float4 b0 = *(const float4*)(bx + k0 + i * 8);
            float4 b1 = *(const float4*)(bx + k0 + i * 8 + 4);
            *(bf16x8*)&Bs[srow][ph * 8] = cvt8(b0, b1);
        }
        __syncthreads();
        #pragma unroll
        for (int kk = 0; kk < 2; ++kk) {
            bf16x8 af[4], bfr[4];
            #pragma unroll
            for (int mt = 0; mt < 4; ++mt) {
                const int row = rw * 64 + mt * 16 + c;
                const int ph = (kk * 4 + q) ^ ((row >> 3) & 3);
                af[mt] = *(const bf16x8*)&As[row][ph * 8];
            }
            #pragma unroll
            for (int nt = 0; nt < 4; ++nt) {
                const int row = cw * 64 + nt * 16 + c;
                const int ph = (kk * 4 + q) ^ ((row >> 3) & 3);
                bfr[nt] = *(const bf16x8*)&Bs[row][ph * 8];
            }
            #pragma unroll
            for (int mt = 0; mt < 4; ++mt)
                #pragma unroll
                for (int nt = 0; nt < 4; ++nt)
                    acc[mt * 4 + nt] = __builtin_amdgcn_mfma_f32_16x16x32_bf16(
                        af[mt], bfr[nt], acc[mt * 4 + nt], 0, 0, 0);
        }
    }

    #pragma unroll
    for (int mt = 0; mt < 4; ++mt)
        #pragma unroll
        for (int nt = 0; nt < 4; ++nt) {
            const int col = cw * 64 + nt * 16 + c;
            const float bb = bias[col];
            f32x4 a = acc[mt * 4 + nt];
            const int mg = m0 + rw * 64 + mt * 16 + q * 4;
            if (nt_idx == 0) {
                #pragma unroll
                for (int r = 0; r < 4; ++r)
                    Qw[(size_t)(mg + r) * QKD + col] = (bf16_t)((a[r] + bb) * QSCALE);
            } else if (nt_idx == 1) {
                #pragma unroll
                for (int r = 0; r < 4; ++r)
                    Kw[(size_t)(mg + r) * QKD + col] = (bf16_t)(a[r] + bb);
            } else {
                const int h = nt_idx - 2;
                const int bidx = mg >> 11, ml = mg & 2047;
                B4 v{ (bf16_t)(a[0] + bb), (bf16_t)(a[1] + bb),
                      (bf16_t)(a[2] + bb), (bf16_t)(a[3] + bb) };
                *(B4*)(Vt + ((size_t)(bidx * HEADS + h) * DV + col) * SEQ + ml) = v;
            }
        }
}

// ---------------------------------------------------------------------------
// Flash attention, 32x32x16 MFMA. One WG = one (b,h) x 128 q-rows, 4 waves
// x 32 rows. S^T = K.Q^T so each lane owns ONE q-row (m = lane&31):
// li is a per-lane scalar; no max-subtraction (scores << exp2 overflow).
// P: C-layout -> Ps[m][n] via 8B packed writes -> b128 A-frag reads.
// ---------------------------------------------------------------------------
__global__ __launch_bounds__(256, 2) void attn2(
    const bf16_t* __restrict__ Q, const bf16_t* __restrict__ K,
    const bf16_t* __restrict__ Vt, const float* __restrict__ X,
    const float* __restrict__ gptr, float* __restrict__ out)
{
    __shared__ alignas(16) bf16_t Vs[128][72];       // [dv][n], swizzled blocks
    __shared__ alignas(16) bf16_t Ps[4][32][72];     // per-wave [m][n]

    const int tid  = threadIdx.x;
    const int lane = tid & 63, wave = tid >> 6;
    const int c5 = lane & 31, q1 = lane >> 5;
    const int bh = blockIdx.y;
    const int b = bh >> 3, h = bh & 7;
    const int m0 = blockIdx.x * 128;
    const int mbase = m0 + wave * 32;

    // Q as B-operand: lane holds Q[mbase+c5][k = q1*8+j] (pre-scaled by QSCALE)
    const bf16x8 qf = *(const bf16x8*)(
        Q + (size_t)(b * SEQ + mbase + c5) * QKD + h * 16 + q1 * 8);

    float li = 0.f;
    f32x16 o[4] = {};

    const bf16_t* Vhead = Vt + (size_t)(b * HEADS + h) * DV * SEQ;
    const bf16_t* Kbase = K + (size_t)(b * SEQ) * QKD + h * 16;

    const int sdv = tid >> 1, sseg = tid & 1;
    const int swv = (sdv >> 3) & 7;
    const int swp = (c5 >> 3) & 3;

    for (int n0 = 0; n0 < SEQ; n0 += 64) {
        __syncthreads();
        {
            const bf16_t* src = Vhead + (size_t)sdv * SEQ + n0 + sseg * 32;
            #pragma unroll
            for (int i = 0; i < 4; ++i) {
                const int ph = (sseg * 4 + i) ^ swv;
                *(bf16x8*)&Vs[sdv][ph * 8] = *(const bf16x8*)(src + i * 8);
            }
        }
        __syncthreads();

        // S^T in two 32x32 blocks; D[row=n][col=m=c5]
        #pragma unroll
        for (int blk = 0; blk < 2; ++blk) {
            const bf16x8 kf = *(const bf16x8*)(
                Kbase + (size_t)(n0 + blk * 32 + c5) * QKD + q1 * 8);
            f32x16 z = {};
            f32x16 s = __builtin_amdgcn_mfma_f32_32x32x16_bf16(kf, qf, z, 0, 0, 0);

            // leaky(max(x,0.2x)) then exp2 (scale folded into Q); accumulate li
            #pragma unroll
            for (int rr = 0; rr < 4; ++rr) {
                float p[4];
                #pragma unroll
                for (int j = 0; j < 4; ++j) {
                    const float sv = s[rr * 4 + j];
                    const float e = __builtin_amdgcn_exp2f(fmaxf(sv, 0.2f * sv));
                    p[j] = e;
                    li += e;
                }
                // n-cols blk*32 + rr*8 + q1*4 + (0..3) of row m=c5: 8B packed
                const int ph = (blk * 4 + rr) ^ swp;
                B4 pv{ (bf16_t)p[0], (bf16_t)p[1], (bf16_t)p[2], (bf16_t)p[3] };
                *(B4*)&Ps[wave][c5][ph * 8 + q1 * 4] = pv;
            }
        }

        // O += P V  (per-wave Ps: no barrier needed, wave-local lgkm ordering)
        #pragma unroll
        for (int kt = 0; kt < 4; ++kt) {
            const int phA = (kt * 2 + q1) ^ swp;
            const bf16x8 pa = *(const bf16x8*)&Ps[wave][c5][phA * 8];
            #pragma unroll
            for (int dvt = 0; dvt < 4; ++dvt) {
                const int dv = dvt * 32 + c5;
                const int phB = (kt * 2 + q1) ^ ((dv >> 3) & 7);
                const bf16x8 vb = *(const bf16x8*)&Vs[dv][phB * 8];
                o[dvt] = __builtin_amdgcn_mfma_f32_32x32x16_bf16(pa, vb, o[dvt], 0, 0, 0);
            }
        }
    }

    // finalize: li partner-half sum, per-row 1/li via shuffle, epilogue
    li += __shfl_xor(li, 32);
    const float inv = 1.f / li;
    const float g = gptr[0];

    float linv[16];
    #pragma unroll
    for (int r = 0; r < 16; ++r) {
        const int row = (r & 3) + 8 * (r >> 2) + 4 * q1;
        linv[r] = __shfl(inv, row);   // inv lives at lane (c5 == row)
    }
    #pragma unroll
    for (int dvt = 0; dvt < 4; ++dvt)
        #pragma unroll
        for (int r = 0; r < 16; ++r) {
            const int row = (r & 3) + 8 * (r >> 2) + 4 * q1;
            const size_t idx = (size_t)(b * SEQ + mbase + row) * CDIM
                             + h * DV + dvt * 32 + c5;
            out[idx] = g * (o[dvt][r] * linv[r]) + X[idx];
        }
}

extern "C" void kernel_launch(void* const* d_in, const int* in_sizes, int n_in,
                              void* d_out, int out_size, void* d_ws, size_t ws_size,
                              hipStream_t stream) {
    const float* X  = (const float*)d_in[0];
    const float* Wq = (const float*)d_in[1];
    const float* bq = (const float*)d_in[2];
    const float* Wk = (const float*)d_in[3];
    const float* bk = (const float*)d_in[4];
    const float* Wv = (const float*)d_in[5];
    const float* bv = (const float*)d_in[6];
    const float* g  = (const float*)d_in[7];
    float* out = (float*)d_out;

    // ws (bf16): Q 2MB + K 2MB + Vt 16.8MB = 21MB (R6 proved ws_size >= this)
    bf16_t* Qw = (bf16_t*)d_ws;
    bf16_t* Kw = Qw + (size_t)MTOT * QKD;
    bf16_t* Vt = Kw + (size_t)MTOT * QKD;

    dim3 blk(256);
    hipLaunchKernelGGL(qkv_gemm2, dim3(10, 64), blk, 0, stream,
                       X, Wq, bq, Wk, bk, Wv, bv, Qw, Kw, Vt);
    hipLaunchKernelGGL(attn2, dim3(SEQ / 128, 32), blk, 0, stream,
                       Qw, Kw, Vt, X, g, out);
}

// Round 8
// 215.227 us; speedup vs baseline: 4.0925x; 1.3172x over previous
//
#include <hip/hip_runtime.h>
#include <hip/hip_bf16.h>

typedef __bf16 bf16_t;
typedef __bf16 bf16x8 __attribute__((ext_vector_type(8)));
typedef float f32x4 __attribute__((ext_vector_type(4)));
typedef float f32x16 __attribute__((ext_vector_type(16)));

#define MTOT 8192
#define CDIM 1024
#define HEADS 8
#define DV 128
#define QKD 128
#define SEQ 2048
#define QSCALE 0.3606737602222409f   // 0.25 * log2(e): softmax scale folded into Q

struct alignas(8) B4 { bf16_t a, b, c, d; };

__device__ inline bf16x8 cvt8(float4 a, float4 b) {
    bf16x8 v = { (bf16_t)a.x, (bf16_t)a.y, (bf16_t)a.z, (bf16_t)a.w,
                 (bf16_t)b.x, (bf16_t)b.y, (bf16_t)b.z, (bf16_t)b.w };
    return v;
}

__device__ inline void gl_lds16(const bf16_t* g, bf16_t* l) {
    __builtin_amdgcn_global_load_lds(
        (const __attribute__((address_space(1))) void*)g,
        (__attribute__((address_space(3))) void*)l, 16, 0, 0);
}

// ---------------------------------------------------------------------------
// fp32 -> bf16, 8 elems/thread
// ---------------------------------------------------------------------------
__global__ __launch_bounds__(256) void cvt_x(
    const float* __restrict__ src, bf16_t* __restrict__ dst, int n8)
{
    int i = blockIdx.x * blockDim.x + threadIdx.x;
    if (i >= n8) return;
    const float4* s = reinterpret_cast<const float4*>(src) + (size_t)i * 2;
    reinterpret_cast<bf16x8*>(dst)[i] = cvt8(s[0], s[1]);
}

// Wq(128) | Wk(128) | Wv(1024) rows -> Wb[1280][1024] bf16
__global__ __launch_bounds__(256) void cvt_w(
    const float* __restrict__ Wq, const float* __restrict__ Wk,
    const float* __restrict__ Wv, bf16_t* __restrict__ Wb)
{
    int i = blockIdx.x * blockDim.x + threadIdx.x;   // 163840 threads
    const float* src;
    if (i < 16384)       src = Wq + (size_t)i * 8;
    else if (i < 32768)  src = Wk + (size_t)(i - 16384) * 8;
    else                 src = Wv + (size_t)(i - 32768) * 8;
    const float4* s = reinterpret_cast<const float4*>(src);
    reinterpret_cast<bf16x8*>(Wb)[i] = cvt8(s[0], s[1]);
}

// ---------------------------------------------------------------------------
// m97-structure GEMM: bf16 in, 128x128 tile, BK=64, global_load_lds(16B).
// grid (10, 64). bx0 -> Q (xQSCALE), bx1 -> K, bx2..9 -> V head (bx-2) transp.
// ---------------------------------------------------------------------------
__global__ __launch_bounds__(256) void qkv_gemm3(
    const bf16_t* __restrict__ Xb, const bf16_t* __restrict__ Wb,
    const float* __restrict__ bq, const float* __restrict__ bk,
    const float* __restrict__ bv,
    bf16_t* __restrict__ Qw, bf16_t* __restrict__ Kw, bf16_t* __restrict__ Vt)
{
    __shared__ bf16_t As[128][64];
    __shared__ bf16_t Bs[128][64];

    const int tid = threadIdx.x;
    const int w = tid >> 6, l = tid & 63;
    const int c = l & 15, q = l >> 4;
    const int rw = w & 1, cw = w >> 1;
    const int bx = blockIdx.x;
    const int m0 = blockIdx.y * 128;

    const bf16_t* Arow = Xb + (size_t)(m0 + w * 8 + (l >> 3)) * CDIM + (l & 7) * 8;
    const bf16_t* Brow = Wb + (size_t)(bx * 128 + w * 8 + (l >> 3)) * CDIM + (l & 7) * 8;

    f32x4 acc[16] = {};

    for (int k0 = 0; k0 < CDIM; k0 += 64) {
        __syncthreads();
        #pragma unroll
        for (int i = 0; i < 4; ++i) {
            gl_lds16(Arow + k0 + (size_t)i * 32 * CDIM, &As[i * 32 + w * 8][0]);
            gl_lds16(Brow + k0 + (size_t)i * 32 * CDIM, &Bs[i * 32 + w * 8][0]);
        }
        __syncthreads();
        #pragma unroll
        for (int kk = 0; kk < 2; ++kk) {
            bf16x8 af[4], bfr[4];
            #pragma unroll
            for (int mt = 0; mt < 4; ++mt)
                af[mt] = *(const bf16x8*)&As[rw * 64 + mt * 16 + c][kk * 32 + q * 8];
            #pragma unroll
            for (int nt = 0; nt < 4; ++nt)
                bfr[nt] = *(const bf16x8*)&Bs[cw * 64 + nt * 16 + c][kk * 32 + q * 8];
            #pragma unroll
            for (int mt = 0; mt < 4; ++mt)
                #pragma unroll
                for (int nt = 0; nt < 4; ++nt)
                    acc[mt * 4 + nt] = __builtin_amdgcn_mfma_f32_16x16x32_bf16(
                        af[mt], bfr[nt], acc[mt * 4 + nt], 0, 0, 0);
        }
    }

    #pragma unroll
    for (int mt = 0; mt < 4; ++mt)
        #pragma unroll
        for (int nt = 0; nt < 4; ++nt) {
            const int cl = cw * 64 + nt * 16 + c;      // col within this bx block
            f32x4 a = acc[mt * 4 + nt];
            const int mg = m0 + rw * 64 + mt * 16 + q * 4;
            if (bx == 0) {
                const float bb = bq[cl];
                #pragma unroll
                for (int r = 0; r < 4; ++r)
                    Qw[(size_t)(mg + r) * QKD + cl] = (bf16_t)((a[r] + bb) * QSCALE);
            } else if (bx == 1) {
                const float bb = bk[cl];
                #pragma unroll
                for (int r = 0; r < 4; ++r)
                    Kw[(size_t)(mg + r) * QKD + cl] = (bf16_t)(a[r] + bb);
            } else {
                const int h = bx - 2;
                const float bb = bv[h * DV + cl];
                const int bidx = mg >> 11, ml = mg & 2047;
                B4 v{ (bf16_t)(a[0] + bb), (bf16_t)(a[1] + bb),
                      (bf16_t)(a[2] + bb), (bf16_t)(a[3] + bb) };
                *(B4*)(Vt + ((size_t)(bidx * HEADS + h) * DV + cl) * SEQ + ml) = v;
            }
        }
}

// ---------------------------------------------------------------------------
// Fallback fp32-input GEMM (R7-proven): LDS-staged 128x128, in-register cvt.
// ---------------------------------------------------------------------------
__global__ __launch_bounds__(256, 2) void qkv_gemm2(
    const float* __restrict__ X,
    const float* __restrict__ Wq, const float* __restrict__ bq,
    const float* __restrict__ Wk, const float* __restrict__ bk,
    const float* __restrict__ Wv, const float* __restrict__ bv,
    bf16_t* __restrict__ Qw, bf16_t* __restrict__ Kw, bf16_t* __restrict__ Vt)
{
    __shared__ alignas(16) bf16_t As[128][72];
    __shared__ alignas(16) bf16_t Bs[128][72];

    const int tid  = threadIdx.x;
    const int lane = tid & 63, wave = tid >> 6;
    const int c = lane & 15, q = lane >> 4;
    const int rw = wave & 1, cw = wave >> 1;
    const int m0 = blockIdx.y * 128;
    const int nt_idx = blockIdx.x;

    const float* W; const float* bias;
    if (nt_idx == 0)      { W = Wq; bias = bq; }
    else if (nt_idx == 1) { W = Wk; bias = bk; }
    else { W = Wv + (size_t)(nt_idx - 2) * DV * CDIM; bias = bv + (nt_idx - 2) * DV; }

    const int srow = tid >> 1, sseg = tid & 1;
    const int swr = (srow >> 3) & 3;
    const float* ax = X + (size_t)(m0 + srow) * CDIM + sseg * 32;
    const float* bxp = W + (size_t)srow * CDIM + sseg * 32;

    f32x4 acc[16] = {};

    for (int k0 = 0; k0 < CDIM; k0 += 64) {
        __syncthreads();
        #pragma unroll
        for (int i = 0; i < 4; ++i) {
            const int ph = (sseg * 4 + i) ^ swr;
            *(bf16x8*)&As[srow][ph * 8] = cvt8(*(const float4*)(ax + k0 + i * 8),
                                               *(const float4*)(ax + k0 + i * 8 + 4));
            *(bf16x8*)&Bs[srow][ph * 8] = cvt8(*(const float4*)(bxp + k0 + i * 8),
                                               *(const float4*)(bxp + k0 + i * 8 + 4));
        }
        __syncthreads();
        #pragma unroll
        for (int kk = 0; kk < 2; ++kk) {
            bf16x8 af[4], bfr[4];
            #pragma unroll
            for (int mt = 0; mt < 4; ++mt) {
                const int row = rw * 64 + mt * 16 + c;
                af[mt] = *(const bf16x8*)&As[row][((kk * 4 + q) ^ ((row >> 3) & 3)) * 8];
            }
            #pragma unroll
            for (int nt = 0; nt < 4; ++nt) {
                const int row = cw * 64 + nt * 16 + c;
                bfr[nt] = *(const bf16x8*)&Bs[row][((kk * 4 + q) ^ ((row >> 3) & 3)) * 8];
            }
            #pragma unroll
            for (int mt = 0; mt < 4; ++mt)
                #pragma unroll
                for (int nt = 0; nt < 4; ++nt)
                    acc[mt * 4 + nt] = __builtin_amdgcn_mfma_f32_16x16x32_bf16(
                        af[mt], bfr[nt], acc[mt * 4 + nt], 0, 0, 0);
        }
    }

    #pragma unroll
    for (int mt = 0; mt < 4; ++mt)
        #pragma unroll
        for (int nt = 0; nt < 4; ++nt) {
            const int col = cw * 64 + nt * 16 + c;
            const float bb = bias[col];
            f32x4 a = acc[mt * 4 + nt];
            const int mg = m0 + rw * 64 + mt * 16 + q * 4;
            if (nt_idx == 0) {
                #pragma unroll
                for (int r = 0; r < 4; ++r)
                    Qw[(size_t)(mg + r) * QKD + col] = (bf16_t)((a[r] + bb) * QSCALE);
            } else if (nt_idx == 1) {
                #pragma unroll
                for (int r = 0; r < 4; ++r)
                    Kw[(size_t)(mg + r) * QKD + col] = (bf16_t)(a[r] + bb);
            } else {
                const int h = nt_idx - 2;
                const int bidx = mg >> 11, ml = mg & 2047;
                B4 v{ (bf16_t)(a[0] + bb), (bf16_t)(a[1] + bb),
                      (bf16_t)(a[2] + bb), (bf16_t)(a[3] + bb) };
                *(B4*)(Vt + ((size_t)(bidx * HEADS + h) * DV + col) * SEQ + ml) = v;
            }
        }
}

// ---------------------------------------------------------------------------
// Flash attention, 32x32x16 MFMA, V/K software-pipelined into registers.
// One WG = one (b,h) x 128 q-rows; lane owns one q-row (S^T = K.Q^T).
// ---------------------------------------------------------------------------
__global__ __launch_bounds__(256, 2) void attn3(
    const bf16_t* __restrict__ Q, const bf16_t* __restrict__ K,
    const bf16_t* __restrict__ Vt, const float* __restrict__ X,
    const float* __restrict__ gptr, float* __restrict__ out)
{
    __shared__ alignas(16) bf16_t Vs[128][72];
    __shared__ alignas(16) bf16_t Ps[4][32][72];

    const int tid  = threadIdx.x;
    const int lane = tid & 63, wave = tid >> 6;
    const int c5 = lane & 31, q1 = lane >> 5;
    const int bh = blockIdx.y;
    const int b = bh >> 3, h = bh & 7;
    const int mbase = blockIdx.x * 128 + wave * 32;

    const bf16x8 qf = *(const bf16x8*)(
        Q + (size_t)(b * SEQ + mbase + c5) * QKD + h * 16 + q1 * 8);

    float li = 0.f;
    f32x16 o[4] = {};

    const bf16_t* Vhead = Vt + (size_t)(b * HEADS + h) * DV * SEQ;
    const bf16_t* Kbase = K + (size_t)(b * SEQ) * QKD + h * 16;

    const int sdv = tid >> 1, sseg = tid & 1;
    const int swv = (sdv >> 3) & 7;
    const int swp = (c5 >> 3) & 3;

    // prologue: prefetch tile 0 into regs
    bf16x8 vreg[4], kreg[2];
    {
        const bf16_t* src = Vhead + (size_t)sdv * SEQ + sseg * 32;
        #pragma unroll
        for (int i = 0; i < 4; ++i) vreg[i] = *(const bf16x8*)(src + i * 8);
        #pragma unroll
        for (int blk = 0; blk < 2; ++blk)
            kreg[blk] = *(const bf16x8*)(Kbase + (size_t)(blk * 32 + c5) * QKD + q1 * 8);
    }

    for (int n0 = 0; n0 < SEQ; n0 += 64) {
        __syncthreads();               // prev tile's Vs consumers done
        #pragma unroll
        for (int i = 0; i < 4; ++i) {
            const int ph = (sseg * 4 + i) ^ swv;
            *(bf16x8*)&Vs[sdv][ph * 8] = vreg[i];
        }
        __syncthreads();               // Vs ready

        const bf16x8 k0f = kreg[0], k1f = kreg[1];
        if (n0 + 64 < SEQ) {           // prefetch next tile during compute
            const bf16_t* src = Vhead + (size_t)sdv * SEQ + n0 + 64 + sseg * 32;
            #pragma unroll
            for (int i = 0; i < 4; ++i) vreg[i] = *(const bf16x8*)(src + i * 8);
            #pragma unroll
            for (int blk = 0; blk < 2; ++blk)
                kreg[blk] = *(const bf16x8*)(
                    Kbase + (size_t)(n0 + 64 + blk * 32 + c5) * QKD + q1 * 8);
        }

        // S^T two 32x32 blocks; leaky+exp2; pack P to LDS (8B stores)
        #pragma unroll
        for (int blk = 0; blk < 2; ++blk) {
            f32x16 z = {};
            f32x16 s = __builtin_amdgcn_mfma_f32_32x32x16_bf16(
                blk ? k1f : k0f, qf, z, 0, 0, 0);
            #pragma unroll
            for (int rr = 0; rr < 4; ++rr) {
                float p[4];
                #pragma unroll
                for (int j = 0; j < 4; ++j) {
                    const float sv = s[rr * 4 + j];
                    const float e = __builtin_amdgcn_exp2f(fmaxf(sv, 0.2f * sv));
                    p[j] = e;
                    li += e;
                }
                const int ph = (blk * 4 + rr) ^ swp;
                B4 pv{ (bf16_t)p[0], (bf16_t)p[1], (bf16_t)p[2], (bf16_t)p[3] };
                *(B4*)&Ps[wave][c5][ph * 8 + q1 * 4] = pv;
            }
        }

        // O += P V (per-wave Ps; wave-local lgkm ordering, no barrier)
        #pragma unroll
        for (int kt = 0; kt < 4; ++kt) {
            const int phA = (kt * 2 + q1) ^ swp;
            const bf16x8 pa = *(const bf16x8*)&Ps[wave][c5][phA * 8];
            #pragma unroll
            for (int dvt = 0; dvt < 4; ++dvt) {
                const int dv = dvt * 32 + c5;
                const int phB = (kt * 2 + q1) ^ ((dv >> 3) & 7);
                const bf16x8 vb = *(const bf16x8*)&Vs[dv][phB * 8];
                o[dvt] = __builtin_amdgcn_mfma_f32_32x32x16_bf16(pa, vb, o[dvt], 0, 0, 0);
            }
        }
    }

    li += __shfl_xor(li, 32);
    const float inv = 1.f / li;
    const float g = gptr[0];

    #pragma unroll
    for (int dvt = 0; dvt < 4; ++dvt)
        #pragma unroll
        for (int r = 0; r < 16; ++r) {
            const int row = (r & 3) + 8 * (r >> 2) + 4 * q1;
            const float linv = __shfl(inv, row);
            const size_t idx = (size_t)(b * SEQ + mbase + row) * CDIM
                             + h * DV + dvt * 32 + c5;
            out[idx] = g * (o[dvt][r] * linv) + X[idx];
        }
}

extern "C" void kernel_launch(void* const* d_in, const int* in_sizes, int n_in,
                              void* d_out, int out_size, void* d_ws, size_t ws_size,
                              hipStream_t stream) {
    const float* X  = (const float*)d_in[0];
    const float* Wq = (const float*)d_in[1];
    const float* bq = (const float*)d_in[2];
    const float* Wk = (const float*)d_in[3];
    const float* bk = (const float*)d_in[4];
    const float* Wv = (const float*)d_in[5];
    const float* bv = (const float*)d_in[6];
    const float* g  = (const float*)d_in[7];
    float* out = (float*)d_out;

    dim3 blk(256);
    const size_t big_elems = (size_t)MTOT * CDIM + 1280 * CDIM
                           + (size_t)MTOT * QKD * 2 + (size_t)MTOT * CDIM;
    const size_t big_ws = big_elems * sizeof(bf16_t);   // 40.4 MB

    if (ws_size >= big_ws) {
        bf16_t* Xb = (bf16_t*)d_ws;                        // 8192x1024
        bf16_t* Wb = Xb + (size_t)MTOT * CDIM;             // 1280x1024
        bf16_t* Qw = Wb + (size_t)1280 * CDIM;             // 8192x128
        bf16_t* Kw = Qw + (size_t)MTOT * QKD;
        bf16_t* Vt = Kw + (size_t)MTOT * QKD;              // 32x128x2048

        hipLaunchKernelGGL(cvt_x, dim3(MTOT * CDIM / 8 / 256), blk, 0, stream,
                           X, Xb, MTOT * CDIM / 8);
        hipLaunchKernelGGL(cvt_w, dim3(1280 * CDIM / 8 / 256), blk, 0, stream,
                           Wq, Wk, Wv, Wb);
        hipLaunchKernelGGL(qkv_gemm3, dim3(10, 64), blk, 0, stream,
                           Xb, Wb, bq, bk, bv, Qw, Kw, Vt);
        hipLaunchKernelGGL(attn3, dim3(SEQ / 128, 32), blk, 0, stream,
                           Qw, Kw, Vt, X, g, out);
    } else {
        // 21 MB fallback (R7-proven)
        bf16_t* Qw = (bf16_t*)d_ws;
        bf16_t* Kw = Qw + (size_t)MTOT * QKD;
        bf16_t* Vt = Kw + (size_t)MTOT * QKD;
        hipLaunchKernelGGL(qkv_gemm2, dim3(10, 64), blk, 0, stream,
                           X, Wq, bq, Wk, bk, Wv, bv, Qw, Kw, Vt);
        hipLaunchKernelGGL(attn3, dim3(SEQ / 128, 32), blk, 0, stream,
                           Qw, Kw, Vt, X, g, out);
    }
}